// Round 10
// baseline (210.228 us; speedup 1.0000x reference)
//
#include <hip/hip_runtime.h>

typedef unsigned int u32;
typedef unsigned long long u64;
typedef __bf16 bf16x8 __attribute__((ext_vector_type(8)));
typedef float f32x4 __attribute__((ext_vector_type(4)));

#define N_TOK 4096   // B*S
#define IN_DIM 2048
#define OUT_DIM 4096
#define NCB 128      // codebooks C
#define NCENT 16     // centroids K
#define VLEN 16      // vec_len V
#define CK 2048      // NCB*NCENT  (GEMM inner dim)
#define KB 64        // K-blocks (CK/32)

static __device__ __forceinline__ unsigned short f2bf(float f) {
  u32 u = __float_as_uint(f);
  u = (u + 0x7FFFu + ((u >> 16) & 1u)) >> 16;  // round-to-nearest-even
  return (unsigned short)u;
}

// ---------------------------------------------------------------------------
// k_prep: lut-build (blocks 0..1023) || Chebyshev argmin (blocks 1024..2047).
// Unchanged (passed R2-R9; not the bottleneck).
// ---------------------------------------------------------------------------
__global__ __launch_bounds__(256) void k_prep(
    const float* __restrict__ x,
    const float* __restrict__ w,
    const float* __restrict__ cents,
    unsigned char* __restrict__ idx,
    char* __restrict__ lutF) {
  __shared__ float cs[16 * 260];  // 16.6KB (argmin path only)
  const int tid = threadIdx.x;
  const int b = blockIdx.x;

  if (b < 1024) {
    // ---- LUT path ----
    const int o0 = (b & 63) * 64;
    const int cg = b >> 6;  // 8-codebook group 0..15
    const int p = tid >> 6;
    const int ol = tid & 63;
    const int o = o0 + ol;

    float acc[2][16];
#pragma unroll
    for (int cc = 0; cc < 2; ++cc)
#pragma unroll
      for (int k = 0; k < 16; ++k) acc[cc][k] = 0.f;

#pragma unroll
    for (int cc = 0; cc < 2; ++cc) {
      const int c = __builtin_amdgcn_readfirstlane(cg * 8 + p * 2 + cc);
      const float* cb = cents + (size_t)c * (NCENT * VLEN);  // scalar loads
#pragma unroll
      for (int v = 0; v < VLEN; ++v) {
        const float wv = w[(size_t)(c * 16 + v) * OUT_DIM + o];
#pragma unroll
        for (int k = 0; k < 16; ++k) acc[cc][k] = fmaf(cb[k * 16 + v], wv, acc[cc][k]);
      }
    }

#pragma unroll
    for (int cc = 0; cc < 2; ++cc) {
      const int c = cg * 8 + p * 2 + cc;
      u32 g[8];
#pragma unroll
      for (int kk = 0; kk < 8; ++kk)
        g[kk] = (u32)f2bf(acc[cc][2 * kk]) | ((u32)f2bf(acc[cc][2 * kk + 1]) << 16);
      char* base = lutF + ((size_t)(o >> 4) * KB + (c >> 1)) * 1024;
      const int l0 = (o & 15) + ((c & 1) * 2) * 16;
      *(uint4*)(base + l0 * 16)        = make_uint4(g[0], g[1], g[2], g[3]);
      *(uint4*)(base + (l0 + 16) * 16) = make_uint4(g[4], g[5], g[6], g[7]);
    }
    return;
  }

  // ---- argmin path ----
  const int a = b - 1024;
  const int n0 = (a & 127) * 32;
  const int cg = a >> 7;  // column chunk 0..7
  const int t = tid >> 4;
  const int cl = tid & 15;

#pragma unroll
  for (int j2 = 0; j2 < 4; ++j2) {
    const int fi = tid + 256 * j2;
    const int row = fi >> 6;
    const int col = (fi & 63) * 4;
    *(float4*)(cs + row * 260 + col) =
        *(const float4*)(cents + ((size_t)(cg * 16 + row)) * 256 + col);
  }

  float xr[2][16];
#pragma unroll
  for (int s = 0; s < 2; ++s)
#pragma unroll
    for (int qq = 0; qq < 4; ++qq) {
      float4 tv = *(const float4*)(x + (size_t)(n0 + t + 16 * s) * IN_DIM +
                                   cg * 256 + cl * 16 + qq * 4);
      xr[s][qq * 4 + 0] = tv.x; xr[s][qq * 4 + 1] = tv.y;
      xr[s][qq * 4 + 2] = tv.z; xr[s][qq * 4 + 3] = tv.w;
    }
  __syncthreads();

  const float* cb = cs + cl * 260;
  int bk0 = 0, bk1 = 0;
  float bd0 = 1e30f, bd1 = 1e30f;
#pragma unroll
  for (int k = 0; k < 16; ++k) {
    float d0 = 0.f, d1 = 0.f;
#pragma unroll
    for (int qq = 0; qq < 4; ++qq) {
      float4 cv = *(const float4*)(cb + k * 16 + qq * 4);
      d0 = fmaxf(d0, fabsf(xr[0][qq * 4 + 0] - cv.x));
      d0 = fmaxf(d0, fabsf(xr[0][qq * 4 + 1] - cv.y));
      d0 = fmaxf(d0, fabsf(xr[0][qq * 4 + 2] - cv.z));
      d0 = fmaxf(d0, fabsf(xr[0][qq * 4 + 3] - cv.w));
      d1 = fmaxf(d1, fabsf(xr[1][qq * 4 + 0] - cv.x));
      d1 = fmaxf(d1, fabsf(xr[1][qq * 4 + 1] - cv.y));
      d1 = fmaxf(d1, fabsf(xr[1][qq * 4 + 2] - cv.z));
      d1 = fmaxf(d1, fabsf(xr[1][qq * 4 + 3] - cv.w));
    }
    if (d0 < bd0) { bd0 = d0; bk0 = k; }
    if (d1 < bd1) { bd1 = d1; bk1 = k; }
  }
  idx[(size_t)(n0 + t) * NCB + cg * 16 + cl] = (unsigned char)bk0;
  idx[(size_t)(n0 + t + 16) * NCB + cg * 16 + cl] = (unsigned char)bk1;
}

// ---------------------------------------------------------------------------
// k_gemm v10: wave-tile 32m x 128n.  A/B ledger across R4/v6/v7 shows the
// one-hot BUILD is ~30 VALU instrs in practice and the VALU pipe (1180 cyc/
// round) exceeds the matrix pipe (990): VALU-bound.  v10 halves builds per
// k-block (2 instead of 4) and amortizes each af over 8 n-tiles; loads grow
// to 8/kb (cheap: v7 proved the load side isn't the cost).  All B state in
// NAMED scalars Bc0..7/Bn0..7 (R1/R4's style that held VGPR; R2/R3 arrays
// collapsed).  acc[2][8]=64 VGPR + B 64 + misc ~= 170-200 -> 2 waves/SIMD
// (launch_bounds(256,2) = 2 blocks/CU, VGPR cap 256).  Same grid/swizzle/
// sIdx/build-arithmetic/D-layout as R4 (all verified).
// ---------------------------------------------------------------------------
__global__ __launch_bounds__(256, 2) void k_gemm(
    const unsigned char* __restrict__ idx,  // [N_TOK][NCB] u8
    const char* __restrict__ Bf,            // fragment-ordered LUT
    const float* __restrict__ bias,
    float* __restrict__ out) {
  __shared__ unsigned char sIdx[128 * 144];  // 18KB, 16B-aligned rows
  const int tid = threadIdx.x;
  const int wave = tid >> 6;
  const int lane = tid & 63;

  // bijective XCD swizzle over grid (32,32)
  const int lin = blockIdx.x + (int)(gridDim.x * blockIdx.y);
  const int slot = lin >> 3;
  const int bx = slot & 31;
  const int by = ((lin & 7) << 2) | (slot >> 5);
  const int m0 = bx * 128;
  const int n0 = by * 128;
  const int wm = wave * 32;  // wave owns 32 m-rows, ALL 128 n-cols

  // ---- stage sIdx (16KB payload, coalesced) ----
#pragma unroll
  for (int j = 0; j < 4; ++j) {
    const int u = tid + 256 * j;
    const int row = u >> 3;
    const int col = (u & 7) * 16;
    *(uint4*)(sIdx + row * 144 + col) =
        *(const uint4*)(idx + (size_t)(m0 + row) * NCB + col);
  }

  // lane constants for the register one-hot build (R4-verified)
  const int h = lane >> 4;
  const u32 sh_e = (u32)((h >> 1) * 8);        // even-j nibble shift
  const u32 sh_o = sh_e + 16u;                 // odd-j nibble shift
  const u32 pxor = (h & 1) ? 0x08080808u : 0u; // par8 pre-xor
  const unsigned char* rb0 = sIdx + (wm + (lane & 15)) * 144;
  const unsigned char* rb1 = rb0 + 16 * 144;

  // 8 B-frag rolling offsets (32-bit, SGPR-base addressing); +=1024/k-block
  u32 bo0 = (u32)(((n0 >> 4) + 0) * (KB * 1024)) + (u32)lane * 16;
  u32 bo1 = bo0 + KB * 1024;
  u32 bo2 = bo1 + KB * 1024;
  u32 bo3 = bo2 + KB * 1024;
  u32 bo4 = bo3 + KB * 1024;
  u32 bo5 = bo4 + KB * 1024;
  u32 bo6 = bo5 + KB * 1024;
  u32 bo7 = bo6 + KB * 1024;

  __syncthreads();  // sIdx visible -- the ONLY barrier in this kernel

  uint4 Bc0 = *(const uint4*)(Bf + bo0);
  uint4 Bc1 = *(const uint4*)(Bf + bo1);
  uint4 Bc2 = *(const uint4*)(Bf + bo2);
  uint4 Bc3 = *(const uint4*)(Bf + bo3);
  uint4 Bc4 = *(const uint4*)(Bf + bo4);
  uint4 Bc5 = *(const uint4*)(Bf + bo5);
  uint4 Bc6 = *(const uint4*)(Bf + bo6);
  uint4 Bc7 = *(const uint4*)(Bf + bo7);
  bo0 += 1024; bo1 += 1024; bo2 += 1024; bo3 += 1024;
  bo4 += 1024; bo5 += 1024; bo6 += 1024; bo7 += 1024;

  f32x4 acc[2][8] = {};

  for (int q = 0; q < 8; ++q) {
    // idx chunk: 16 codebooks (8 k-blocks) for this wave's 2 m-tiles;
    // broadcast LDS reads, pre-XOR'd
    uint4 ch0 = *(const uint4*)(rb0 + q * 16);
    uint4 ch1 = *(const uint4*)(rb1 + q * 16);
    ch0.x ^= pxor; ch0.y ^= pxor; ch0.z ^= pxor; ch0.w ^= pxor;
    ch1.x ^= pxor; ch1.y ^= pxor; ch1.z ^= pxor; ch1.w ^= pxor;

#pragma unroll
    for (int j = 0; j < 8; ++j) {
      // prefetch next k-block's B (q=7,j=7 over-reads 1KB into the idx
      // region: allocated, values dead)
      uint4 Bn0 = *(const uint4*)(Bf + bo0);
      uint4 Bn1 = *(const uint4*)(Bf + bo1);
      uint4 Bn2 = *(const uint4*)(Bf + bo2);
      uint4 Bn3 = *(const uint4*)(Bf + bo3);
      uint4 Bn4 = *(const uint4*)(Bf + bo4);
      uint4 Bn5 = *(const uint4*)(Bf + bo5);
      uint4 Bn6 = *(const uint4*)(Bf + bo6);
      uint4 Bn7 = *(const uint4*)(Bf + bo7);
      bo0 += 1024; bo1 += 1024; bo2 += 1024; bo3 += 1024;
      bo4 += 1024; bo5 += 1024; bo6 += 1024; bo7 += 1024;

      // build 2 one-hot A fragments in registers (R4-verified arithmetic)
      const u32 sh = (j & 1) ? sh_o : sh_e;
      const u32 w0 = (j >> 1) == 0 ? ch0.x : (j >> 1) == 1 ? ch0.y
                   : (j >> 1) == 2 ? ch0.z : ch0.w;
      const u32 w1 = (j >> 1) == 0 ? ch1.x : (j >> 1) == 1 ? ch1.y
                   : (j >> 1) == 2 ? ch1.z : ch1.w;
      const u32 uu0 = (w0 >> sh) & 15u;
      const u32 uu1 = (w1 >> sh) & 15u;
      const u64 dbl0 = 0x3F80ull << ((uu0 << 4) & 63u);
      const u64 dbl1 = 0x3F80ull << ((uu1 << 4) & 63u);
      const u64 lo0 = (uu0 < 4u) ? dbl0 : 0ull;
      const u64 hi0 = ((uu0 - 4u) < 4u) ? dbl0 : 0ull;  // unsigned wrap
      const u64 lo1 = (uu1 < 4u) ? dbl1 : 0ull;
      const u64 hi1 = ((uu1 - 4u) < 4u) ? dbl1 : 0ull;
      uint4 f0, f1;
      f0.x = (u32)lo0; f0.y = (u32)(lo0 >> 32);
      f0.z = (u32)hi0; f0.w = (u32)(hi0 >> 32);
      f1.x = (u32)lo1; f1.y = (u32)(lo1 >> 32);
      f1.z = (u32)hi1; f1.w = (u32)(hi1 >> 32);
      const bf16x8 af0 = *(const bf16x8*)&f0;
      const bf16x8 af1 = *(const bf16x8*)&f1;

      acc[0][0] = __builtin_amdgcn_mfma_f32_16x16x32_bf16(
          af0, *(const bf16x8*)&Bc0, acc[0][0], 0, 0, 0);
      acc[1][0] = __builtin_amdgcn_mfma_f32_16x16x32_bf16(
          af1, *(const bf16x8*)&Bc0, acc[1][0], 0, 0, 0);
      acc[0][1] = __builtin_amdgcn_mfma_f32_16x16x32_bf16(
          af0, *(const bf16x8*)&Bc1, acc[0][1], 0, 0, 0);
      acc[1][1] = __builtin_amdgcn_mfma_f32_16x16x32_bf16(
          af1, *(const bf16x8*)&Bc1, acc[1][1], 0, 0, 0);
      acc[0][2] = __builtin_amdgcn_mfma_f32_16x16x32_bf16(
          af0, *(const bf16x8*)&Bc2, acc[0][2], 0, 0, 0);
      acc[1][2] = __builtin_amdgcn_mfma_f32_16x16x32_bf16(
          af1, *(const bf16x8*)&Bc2, acc[1][2], 0, 0, 0);
      acc[0][3] = __builtin_amdgcn_mfma_f32_16x16x32_bf16(
          af0, *(const bf16x8*)&Bc3, acc[0][3], 0, 0, 0);
      acc[1][3] = __builtin_amdgcn_mfma_f32_16x16x32_bf16(
          af1, *(const bf16x8*)&Bc3, acc[1][3], 0, 0, 0);
      acc[0][4] = __builtin_amdgcn_mfma_f32_16x16x32_bf16(
          af0, *(const bf16x8*)&Bc4, acc[0][4], 0, 0, 0);
      acc[1][4] = __builtin_amdgcn_mfma_f32_16x16x32_bf16(
          af1, *(const bf16x8*)&Bc4, acc[1][4], 0, 0, 0);
      acc[0][5] = __builtin_amdgcn_mfma_f32_16x16x32_bf16(
          af0, *(const bf16x8*)&Bc5, acc[0][5], 0, 0, 0);
      acc[1][5] = __builtin_amdgcn_mfma_f32_16x16x32_bf16(
          af1, *(const bf16x8*)&Bc5, acc[1][5], 0, 0, 0);
      acc[0][6] = __builtin_amdgcn_mfma_f32_16x16x32_bf16(
          af0, *(const bf16x8*)&Bc6, acc[0][6], 0, 0, 0);
      acc[1][6] = __builtin_amdgcn_mfma_f32_16x16x32_bf16(
          af1, *(const bf16x8*)&Bc6, acc[1][6], 0, 0, 0);
      acc[0][7] = __builtin_amdgcn_mfma_f32_16x16x32_bf16(
          af0, *(const bf16x8*)&Bc7, acc[0][7], 0, 0, 0);
      acc[1][7] = __builtin_amdgcn_mfma_f32_16x16x32_bf16(
          af1, *(const bf16x8*)&Bc7, acc[1][7], 0, 0, 0);

      Bc0 = Bn0; Bc1 = Bn1; Bc2 = Bn2; Bc3 = Bn3;  // SSA-renamed by unroll
      Bc4 = Bn4; Bc5 = Bn5; Bc6 = Bn6; Bc7 = Bn7;
    }
  }

  // epilogue: D layout col=lane&15, row=(lane>>4)*4+r  [m89-verified]
  const int col = lane & 15;
  const int rq = (lane >> 4) * 4;
  float bj[8];
#pragma unroll
  for (int jj = 0; jj < 8; ++jj) bj[jj] = bias[n0 + jj * 16 + col];
#pragma unroll
  for (int i = 0; i < 2; ++i) {
    const int gm = m0 + wm + i * 16 + rq;
#pragma unroll
    for (int jj = 0; jj < 8; ++jj) {
      const int gn = n0 + jj * 16 + col;
      float* op = out + (size_t)gm * OUT_DIM + gn;
#pragma unroll
      for (int r = 0; r < 4; ++r) op[(size_t)r * OUT_DIM] = acc[i][jj][r] + bj[jj];
    }
  }
}

// ---------------------------------------------------------------------------
extern "C" void kernel_launch(void* const* d_in, const int* in_sizes, int n_in,
                              void* d_out, int out_size, void* d_ws, size_t ws_size,
                              hipStream_t stream) {
  (void)in_sizes; (void)n_in; (void)out_size; (void)ws_size;
  const float* x      = (const float*)d_in[0];
  const float* weight = (const float*)d_in[1];
  const float* cents  = (const float*)d_in[2];
  const float* bias   = (const float*)d_in[3];
  // d_in[4] = vec_len (16), hardcoded

  char* lutF = (char*)d_ws;                                              // 16.8MB
  unsigned char* idx = (unsigned char*)d_ws + (size_t)OUT_DIM * CK * 2;  // 512KB
  float* out = (float*)d_out;

  k_prep<<<dim3(2048), 256, 0, stream>>>(x, weight, cents, idx, lutF);
  k_gemm<<<dim3(32, 32), 256, 0, stream>>>(idx, lutF, bias, out);
}

// Round 11
// 172.080 us; speedup vs baseline: 1.2217x; 1.2217x over previous
//
#include <hip/hip_runtime.h>

typedef unsigned int u32;
typedef unsigned long long u64;
typedef __bf16 bf16x8 __attribute__((ext_vector_type(8)));
typedef float f32x4 __attribute__((ext_vector_type(4)));

#define N_TOK 4096   // B*S
#define IN_DIM 2048
#define OUT_DIM 4096
#define NCB 128      // codebooks C
#define NCENT 16     // centroids K
#define VLEN 16      // vec_len V
#define CK 2048      // NCB*NCENT  (GEMM inner dim)
#define KB 64        // K-blocks (CK/32)

static __device__ __forceinline__ unsigned short f2bf(float f) {
  u32 u = __float_as_uint(f);
  u = (u + 0x7FFFu + ((u >> 16) & 1u)) >> 16;  // round-to-nearest-even
  return (unsigned short)u;
}

// ---------------------------------------------------------------------------
// k_prep: lut-build (blocks 0..1023) || Chebyshev argmin (blocks 1024..2047).
// Unchanged (passed R2-R10; not the bottleneck).
// ---------------------------------------------------------------------------
__global__ __launch_bounds__(256) void k_prep(
    const float* __restrict__ x,
    const float* __restrict__ w,
    const float* __restrict__ cents,
    unsigned char* __restrict__ idx,
    char* __restrict__ lutF) {
  __shared__ float cs[16 * 260];  // 16.6KB (argmin path only)
  const int tid = threadIdx.x;
  const int b = blockIdx.x;

  if (b < 1024) {
    // ---- LUT path ----
    const int o0 = (b & 63) * 64;
    const int cg = b >> 6;  // 8-codebook group 0..15
    const int p = tid >> 6;
    const int ol = tid & 63;
    const int o = o0 + ol;

    float acc[2][16];
#pragma unroll
    for (int cc = 0; cc < 2; ++cc)
#pragma unroll
      for (int k = 0; k < 16; ++k) acc[cc][k] = 0.f;

#pragma unroll
    for (int cc = 0; cc < 2; ++cc) {
      const int c = __builtin_amdgcn_readfirstlane(cg * 8 + p * 2 + cc);
      const float* cb = cents + (size_t)c * (NCENT * VLEN);  // scalar loads
#pragma unroll
      for (int v = 0; v < VLEN; ++v) {
        const float wv = w[(size_t)(c * 16 + v) * OUT_DIM + o];
#pragma unroll
        for (int k = 0; k < 16; ++k) acc[cc][k] = fmaf(cb[k * 16 + v], wv, acc[cc][k]);
      }
    }

#pragma unroll
    for (int cc = 0; cc < 2; ++cc) {
      const int c = cg * 8 + p * 2 + cc;
      u32 g[8];
#pragma unroll
      for (int kk = 0; kk < 8; ++kk)
        g[kk] = (u32)f2bf(acc[cc][2 * kk]) | ((u32)f2bf(acc[cc][2 * kk + 1]) << 16);
      char* base = lutF + ((size_t)(o >> 4) * KB + (c >> 1)) * 1024;
      const int l0 = (o & 15) + ((c & 1) * 2) * 16;
      *(uint4*)(base + l0 * 16)        = make_uint4(g[0], g[1], g[2], g[3]);
      *(uint4*)(base + (l0 + 16) * 16) = make_uint4(g[4], g[5], g[6], g[7]);
    }
    return;
  }

  // ---- argmin path ----
  const int a = b - 1024;
  const int n0 = (a & 127) * 32;
  const int cg = a >> 7;  // column chunk 0..7
  const int t = tid >> 4;
  const int cl = tid & 15;

#pragma unroll
  for (int j2 = 0; j2 < 4; ++j2) {
    const int fi = tid + 256 * j2;
    const int row = fi >> 6;
    const int col = (fi & 63) * 4;
    *(float4*)(cs + row * 260 + col) =
        *(const float4*)(cents + ((size_t)(cg * 16 + row)) * 256 + col);
  }

  float xr[2][16];
#pragma unroll
  for (int s = 0; s < 2; ++s)
#pragma unroll
    for (int qq = 0; qq < 4; ++qq) {
      float4 tv = *(const float4*)(x + (size_t)(n0 + t + 16 * s) * IN_DIM +
                                   cg * 256 + cl * 16 + qq * 4);
      xr[s][qq * 4 + 0] = tv.x; xr[s][qq * 4 + 1] = tv.y;
      xr[s][qq * 4 + 2] = tv.z; xr[s][qq * 4 + 3] = tv.w;
    }
  __syncthreads();

  const float* cb = cs + cl * 260;
  int bk0 = 0, bk1 = 0;
  float bd0 = 1e30f, bd1 = 1e30f;
#pragma unroll
  for (int k = 0; k < 16; ++k) {
    float d0 = 0.f, d1 = 0.f;
#pragma unroll
    for (int qq = 0; qq < 4; ++qq) {
      float4 cv = *(const float4*)(cb + k * 16 + qq * 4);
      d0 = fmaxf(d0, fabsf(xr[0][qq * 4 + 0] - cv.x));
      d0 = fmaxf(d0, fabsf(xr[0][qq * 4 + 1] - cv.y));
      d0 = fmaxf(d0, fabsf(xr[0][qq * 4 + 2] - cv.z));
      d0 = fmaxf(d0, fabsf(xr[0][qq * 4 + 3] - cv.w));
      d1 = fmaxf(d1, fabsf(xr[1][qq * 4 + 0] - cv.x));
      d1 = fmaxf(d1, fabsf(xr[1][qq * 4 + 1] - cv.y));
      d1 = fmaxf(d1, fabsf(xr[1][qq * 4 + 2] - cv.z));
      d1 = fmaxf(d1, fabsf(xr[1][qq * 4 + 3] - cv.w));
    }
    if (d0 < bd0) { bd0 = d0; bk0 = k; }
    if (d1 < bd1) { bd1 = d1; bk1 = k; }
  }
  idx[(size_t)(n0 + t) * NCB + cg * 16 + cl] = (unsigned char)bk0;
  idx[(size_t)(n0 + t + 16) * NCB + cg * 16 + cl] = (unsigned char)bk1;
}

// ---------------------------------------------------------------------------
// k_gemm = R4's best-measured kernel, verbatim (62.9us, MfmaUtil 43%,
// VALU 46%, VGPR 104).  Final ledger: v6 LDS-table 66.9 / v7 128x32 83.4 /
// v8 dist-2 68.5 / v9 setprio 64.5 / v10 32x128 99.0 -- all regressed or
// null.  Per-SIMD arithmetic (m06: ~19.4 cyc per 16x16x32 MFMA) shows this
// config runs at ~85-90% of the matrix-pipe throughput available at its
// achieved occupancy; the remaining gap needs an occupancy/shape rewrite
// that measured worse in every direction tried.
// ---------------------------------------------------------------------------
__global__ __launch_bounds__(256) void k_gemm(
    const unsigned char* __restrict__ idx,  // [N_TOK][NCB] u8
    const char* __restrict__ Bf,            // fragment-ordered LUT
    const float* __restrict__ bias,
    float* __restrict__ out) {
  __shared__ unsigned char sIdx[128 * 144];  // 18KB, 16B-aligned rows
  const int tid = threadIdx.x;
  const int wave = tid >> 6;
  const int lane = tid & 63;

  // bijective XCD swizzle over grid (32,32)
  const int lin = blockIdx.x + (int)(gridDim.x * blockIdx.y);
  const int slot = lin >> 3;
  const int bx = slot & 31;
  const int by = ((lin & 7) << 2) | (slot >> 5);
  const int m0 = bx * 128;
  const int n0 = by * 128;
  const int wm = (wave >> 1) * 64;
  const int wn = (wave & 1) * 64;

  // ---- stage sIdx (16KB payload, coalesced) ----
#pragma unroll
  for (int j = 0; j < 4; ++j) {
    const int u = tid + 256 * j;
    const int row = u >> 3;
    const int col = (u & 7) * 16;
    *(uint4*)(sIdx + row * 144 + col) =
        *(const uint4*)(idx + (size_t)(m0 + row) * NCB + col);
  }

  // lane constants for the register one-hot build (R4-verified)
  const int h = lane >> 4;
  const u32 sh_e = (u32)((h >> 1) * 8);        // even-j nibble shift
  const u32 sh_o = sh_e + 16u;                 // odd-j nibble shift
  const u32 pxor = (h & 1) ? 0x08080808u : 0u; // par8 pre-xor
  const unsigned char* rb[4];
#pragma unroll
  for (int i = 0; i < 4; ++i) rb[i] = sIdx + (wm + i * 16 + (lane & 15)) * 144;

  // B-frag rolling offsets (32-bit, SGPR-base addressing); +=1024 per k-block
  const int tb = (n0 >> 4) + (wn >> 4);
  u32 bo0 = (u32)(tb + 0) * (KB * 1024) + (u32)lane * 16;
  u32 bo1 = bo0 + KB * 1024;
  u32 bo2 = bo1 + KB * 1024;
  u32 bo3 = bo2 + KB * 1024;

  __syncthreads();  // sIdx visible -- the ONLY barrier in this kernel

  uint4 Bc0 = *(const uint4*)(Bf + bo0);
  uint4 Bc1 = *(const uint4*)(Bf + bo1);
  uint4 Bc2 = *(const uint4*)(Bf + bo2);
  uint4 Bc3 = *(const uint4*)(Bf + bo3);
  bo0 += 1024; bo1 += 1024; bo2 += 1024; bo3 += 1024;

  f32x4 acc[4][4] = {};

  for (int q = 0; q < 8; ++q) {
    // idx chunk: 16 codebooks (8 k-blocks); broadcast LDS reads, pre-XOR'd
    uint4 ch[4];
#pragma unroll
    for (int i = 0; i < 4; ++i) {
      ch[i] = *(const uint4*)(rb[i] + q * 16);
      ch[i].x ^= pxor; ch[i].y ^= pxor; ch[i].z ^= pxor; ch[i].w ^= pxor;
    }

#pragma unroll
    for (int j = 0; j < 8; ++j) {
      // prefetch next k-block's B (q=7,j=7 over-reads 1KB into the idx
      // region: allocated, values dead)
      uint4 Bn0 = *(const uint4*)(Bf + bo0);
      uint4 Bn1 = *(const uint4*)(Bf + bo1);
      uint4 Bn2 = *(const uint4*)(Bf + bo2);
      uint4 Bn3 = *(const uint4*)(Bf + bo3);
      bo0 += 1024; bo1 += 1024; bo2 += 1024; bo3 += 1024;

      // build 4 one-hot A fragments in registers (~11 VALU each, trimmed)
      const u32 sh = (j & 1) ? sh_o : sh_e;
      bf16x8 af[4];
#pragma unroll
      for (int i = 0; i < 4; ++i) {
        const u32 word = (j >> 1) == 0 ? ch[i].x
                       : (j >> 1) == 1 ? ch[i].y
                       : (j >> 1) == 2 ? ch[i].z
                                       : ch[i].w;
        const u32 uu = (word >> sh) & 15u;
        const u32 sa = (uu << 4) & 63u;
        const u64 dbl = 0x3F80ull << sa;
        const u64 lo = (uu < 4u) ? dbl : 0ull;
        const u64 hi = ((uu - 4u) < 4u) ? dbl : 0ull;  // unsigned wrap
        uint4 f;
        f.x = (u32)lo; f.y = (u32)(lo >> 32);
        f.z = (u32)hi; f.w = (u32)(hi >> 32);
        af[i] = *(bf16x8*)&f;
      }

#pragma unroll
      for (int i = 0; i < 4; ++i) {
        acc[i][0] = __builtin_amdgcn_mfma_f32_16x16x32_bf16(
            af[i], *(const bf16x8*)&Bc0, acc[i][0], 0, 0, 0);
        acc[i][1] = __builtin_amdgcn_mfma_f32_16x16x32_bf16(
            af[i], *(const bf16x8*)&Bc1, acc[i][1], 0, 0, 0);
        acc[i][2] = __builtin_amdgcn_mfma_f32_16x16x32_bf16(
            af[i], *(const bf16x8*)&Bc2, acc[i][2], 0, 0, 0);
        acc[i][3] = __builtin_amdgcn_mfma_f32_16x16x32_bf16(
            af[i], *(const bf16x8*)&Bc3, acc[i][3], 0, 0, 0);
      }

      Bc0 = Bn0; Bc1 = Bn1; Bc2 = Bn2; Bc3 = Bn3;  // SSA-renamed by unroll
    }
  }

  // epilogue: D layout col=lane&15, row=(lane>>4)*4+r  [m89-verified]
  const int col = lane & 15;
  const int rq = (lane >> 4) * 4;
  float bj[4];
#pragma unroll
  for (int j = 0; j < 4; ++j) bj[j] = bias[n0 + wn + j * 16 + col];
#pragma unroll
  for (int i = 0; i < 4; ++i) {
    const int gm = m0 + wm + i * 16 + rq;
#pragma unroll
    for (int j = 0; j < 4; ++j) {
      const int gn = n0 + wn + j * 16 + col;
      float* op = out + (size_t)gm * OUT_DIM + gn;
#pragma unroll
      for (int r = 0; r < 4; ++r) op[(size_t)r * OUT_DIM] = acc[i][j][r] + bj[j];
    }
  }
}

// ---------------------------------------------------------------------------
extern "C" void kernel_launch(void* const* d_in, const int* in_sizes, int n_in,
                              void* d_out, int out_size, void* d_ws, size_t ws_size,
                              hipStream_t stream) {
  (void)in_sizes; (void)n_in; (void)out_size; (void)ws_size;
  const float* x      = (const float*)d_in[0];
  const float* weight = (const float*)d_in[1];
  const float* cents  = (const float*)d_in[2];
  const float* bias   = (const float*)d_in[3];
  // d_in[4] = vec_len (16), hardcoded

  char* lutF = (char*)d_ws;                                              // 16.8MB
  unsigned char* idx = (unsigned char*)d_ws + (size_t)OUT_DIM * CK * 2;  // 512KB
  float* out = (float*)d_out;

  k_prep<<<dim3(2048), 256, 0, stream>>>(x, weight, cents, idx, lutF);
  k_gemm<<<dim3(32, 32), 256, 0, stream>>>(idx, lutF, bias, out);
}